// Round 17
// baseline (658.985 us; speedup 1.0000x reference)
//
#include <hip/hip_runtime.h>
#include <hip/hip_fp16.h>

#define WPB 4     // waves per block in agg
#define CHUNK 24  // edges staged per buffer (avg deg 16; P(deg>24)~2%)
#define MTILE 8   // nodes per wave in mlp/final
#define AGG_BLOCKS 1280
#define MLP_BLOCKS 1024
#define LOG2E 1.4426950408889634f

typedef _Float16 h2 __attribute__((ext_vector_type(2)));

static __device__ __forceinline__ float fdot2f(h2 a, h2 b, float c) {
#if __has_builtin(__builtin_amdgcn_fdot2)
  return __builtin_amdgcn_fdot2(a, b, c, false);
#else
  return c + (float)a[0] * (float)b[0] + (float)a[1] * (float)b[1];
#endif
}

static __device__ __forceinline__ void gload_lds16(const void* gp, void* lp) {
  __builtin_amdgcn_global_load_lds((const __attribute__((address_space(1))) void*)gp,
                                   (__attribute__((address_space(3))) void*)lp, 16, 0, 0);
}

static __device__ __forceinline__ float wred(float v) {
#pragma unroll
  for (int o = 32; o > 0; o >>= 1) v += __shfl_xor(v, o, 64);
  return v;
}

// h0[n,d] = x[n,:8] @ node_W[:,d] + node_b[d], stored fp16
__global__ void node_enc_kernel(const float* __restrict__ x, const float* __restrict__ W,
                                const float* __restrict__ b, __half* __restrict__ z, int N) {
  int t = blockIdx.x * blockDim.x + threadIdx.x;
  if (t >= N * 64) return;
  int n = t >> 6, d = t & 63;
  float acc = b[d];
#pragma unroll
  for (int k = 0; k < 8; ++k) acc = fmaf(x[n * 8 + k], W[k * 64 + d], acc);
  z[t] = __float2half(acc);
}

__global__ void hist_kernel(const int* __restrict__ dst, int* __restrict__ cnt, int E) {
  int e = blockIdx.x * blockDim.x + threadIdx.x;
  if (e < E) atomicAdd(&cnt[dst[e]], 1);
}

// --- multi-block exclusive scan of cnt[0..n) -> off[0..n] ---
__global__ void scanA_kernel(const int* __restrict__ cnt, int* __restrict__ off,
                             int* __restrict__ bsum, int n) {
  __shared__ int lds[1024];
  int tid = threadIdx.x;
  int i = blockIdx.x * 1024 + tid;
  int v = (i < n) ? cnt[i] : 0;
  lds[tid] = v;
  __syncthreads();
  for (int ofs = 1; ofs < 1024; ofs <<= 1) {
    int tv = (tid >= ofs) ? lds[tid - ofs] : 0;
    __syncthreads();
    lds[tid] += tv;
    __syncthreads();
  }
  if (i < n) off[i] = lds[tid] - v;  // local exclusive
  if (tid == 1023) bsum[blockIdx.x] = lds[1023];
}

__global__ void scanB_kernel(const int* __restrict__ bsum, int* __restrict__ boff, int nb) {
  if (threadIdx.x == 0) {
    int acc = 0;
    for (int i = 0; i < nb; ++i) {
      boff[i] = acc;
      acc += bsum[i];
    }
    boff[nb] = acc;
  }
}

__global__ void scanC_kernel(int* __restrict__ off, const int* __restrict__ boff, int n, int nb) {
  int i = blockIdx.x * blockDim.x + threadIdx.x;
  if (i < n)
    off[i] += boff[i >> 10];
  else if (i == n)
    off[n] = boff[nb];
}

// scatter src ids + fp16 edge features (16B rows) into CSR order (sequential agg stream).
__global__ void scatter_kernel(const int* __restrict__ src, const int* __restrict__ dst,
                               const int* __restrict__ off, int* __restrict__ cur,
                               int* __restrict__ csr_src, const float* __restrict__ edge_attr,
                               __half* __restrict__ ecsr, int E) {
  int e = blockIdx.x * blockDim.x + threadIdx.x;
  if (e >= E) return;
  int dn = dst[e];
  int p = atomicAdd(&cur[dn], 1);
  int idx = off[dn] + p;
  csr_src[idx] = src[e];
  const float4* ap = reinterpret_cast<const float4*>(edge_attr + (size_t)e * 8);
  float4 a0 = ap[0], a1 = ap[1];
  __half2 q0 = __floats2half2_rn(a0.x, a0.y);
  __half2 q1 = __floats2half2_rn(a0.z, a0.w);
  __half2 q2 = __floats2half2_rn(a1.x, a1.y);
  __half2 q3 = __floats2half2_rn(a1.z, a1.w);
  uint4 row;
  row.x = __builtin_bit_cast(unsigned int, q0);
  row.y = __builtin_bit_cast(unsigned int, q1);
  row.z = __builtin_bit_cast(unsigned int, q2);
  row.w = __builtin_bit_cast(unsigned int, q3);
  *reinterpret_cast<uint4*>(ecsr + (size_t)idx * 8) = row;
}

// Pack weights to fp16 half2 pairs along the reduction dim in [red][out] orientation.
__global__ void wprep_kernel(const float* __restrict__ W1, const float* __restrict__ W2,
                             const float* __restrict__ linW, __half2* __restrict__ w1p,
                             __half2* __restrict__ w2p, __half2* __restrict__ linp) {
  int t = blockIdx.x * blockDim.x + threadIdx.x;
  const int tot1 = 5 * 32 * 128;
  if (t < tot1) {
    int l = t / 4096, r = t % 4096;
    int g = r / 128, j = r % 128;
    const float* base = W1 + l * 8192;
    w1p[t] = __floats2half2_rn(base[(2 * g) * 128 + j], base[(2 * g + 1) * 128 + j]);
  } else if (t < 2 * tot1) {
    int u = t - tot1;
    int l = u / 4096, r = u % 4096;
    int g = r / 64, j = r % 64;
    const float* base = W2 + l * 8192;
    w2p[u] = __floats2half2_rn(base[(2 * g) * 64 + j], base[(2 * g + 1) * 64 + j]);
  } else if (t < 2 * tot1 + 32 * 112) {
    int u = t - 2 * tot1;
    int g = u / 112, o = u % 112;
    linp[u] = __floats2half2_rn(linW[(2 * g) * 112 + o], linW[(2 * g + 1) * 112 + o]);
  }
}

#define EAH(R)                                                                     \
  fdot2f(__builtin_bit_cast(h2, (R).w), eWh[3],                                    \
         fdot2f(__builtin_bit_cast(h2, (R).z), eWh[2],                             \
                fdot2f(__builtin_bit_cast(h2, (R).y), eWh[1],                      \
                       fdot2f(__builtin_bit_cast(h2, (R).x), eWh[0], ebd))))

// 4-edge online-softmax step (R12-proven form); logits pre-scaled by log2(e).
#define BATCH4(ZP, EH, EO, R4)                                                   \
  {                                                                              \
    float z0 = __half2float(ZP[(EO + 0) * 64 + d]);                              \
    float z1 = __half2float(ZP[(EO + 1) * 64 + d]);                              \
    float z2 = __half2float(ZP[(EO + 2) * 64 + d]);                              \
    float z3 = __half2float(ZP[(EO + 3) * 64 + d]);                              \
    const float4* fp4 = reinterpret_cast<const float4*>(EH + (size_t)(EO)*8);    \
    float4 r0 = fp4[0], r1 = fp4[1], r2 = fp4[2], r3 = fp4[3];                   \
    float ea0 = EAH(r0), ea1 = EAH(r1), ea2 = EAH(r2), ea3 = EAH(r3);            \
    float ms0 = fmaxf(z0 + ea0, 0.f) + 1e-7f;                                    \
    float ms1 = fmaxf(z1 + ea1, 0.f) + 1e-7f;                                    \
    float ms2 = fmaxf(z2 + ea2, 0.f) + 1e-7f;                                    \
    float ms3 = fmaxf(z3 + ea3, 0.f) + 1e-7f;                                    \
    float l0 = ms0 * tlog, l1 = ms1 * tlog, l2 = ms2 * tlog, l3 = ms3 * tlog;    \
    if (R4 < 4) {                                                                \
      if (R4 < 2) l1 = -__builtin_inff();                                        \
      if (R4 < 3) l2 = -__builtin_inff();                                        \
      l3 = -__builtin_inff();                                                    \
    }                                                                            \
    float bm = fmaxf(fmaxf(l0, l1), fmaxf(l2, l3));                              \
    float nm = fmaxf(m, bm);                                                     \
    float sc = exp2f(m - nm);                                                    \
    float p0 = exp2f(l0 - nm), p1 = exp2f(l1 - nm);                              \
    float p2 = exp2f(l2 - nm), p3 = exp2f(l3 - nm);                              \
    s = fmaf(s, sc, (p0 + p1) + (p2 + p3));                                      \
    w = fmaf(w, sc, fmaf(p0, ms0, p1 * ms1) + fmaf(p2, ms2, p3 * ms3));          \
    m = nm;                                                                      \
  }

#define STAGE_NODE(SRCREG, BEGV, DEGV, BUF)                                           \
  {                                                                                   \
    int rem_ = min(CHUNK, DEGV);                                                      \
    int n8_ = (rem_ + 7) >> 3;                                                        \
    char* zb_ = (char*)&zst[wv][BUF][0];                                              \
    for (int p_ = 0; p_ < n8_; ++p_) {                                                \
      int sl_ = min((p_ << 3) + slot8, rem_ - 1);                                     \
      int sn_ = __shfl(SRCREG, sl_);                                                  \
      gload_lds16((const char*)(zin + ((size_t)sn_ << 6)) + sub16, zb_ + (p_ << 10)); \
    }                                                                                 \
    gload_lds16((const char*)ef + ((size_t)(BEGV) + min(d, rem_ - 1)) * 16,           \
                (char*)&efst[wv][BUF][0]);                                            \
  }

// One wave handles nodes gw, gw+TW, ... with a 2-deep cross-node staging pipeline.
__global__ void agg_kernel(const __half* __restrict__ zin, __half* __restrict__ aggh,
                           const int* __restrict__ off, const int* __restrict__ csr_src,
                           const __half* __restrict__ ef, const float* __restrict__ edge_W,
                           const float* __restrict__ edge_b, const float* __restrict__ tptr,
                           int layer, int N, int TW) {
  __shared__ __align__(16) __half zst[WPB][2][CHUNK * 64];  // 2 x 3 KB per wave
  __shared__ __align__(16) __half efst[WPB][2][64 * 8];     // 2 x 1 KB per wave
  int wv = threadIdx.x >> 6, d = threadIdx.x & 63;
  int gw = blockIdx.x * WPB + wv;
  if (gw >= N) return;
  h2 eWh[4];
#pragma unroll
  for (int q = 0; q < 4; ++q) {
    __half2 hp = __floats2half2_rn(edge_W[(2 * q) * 64 + d], edge_W[(2 * q + 1) * 64 + d]);
    eWh[q] = __builtin_bit_cast(h2, hp);
  }
  float ebd = edge_b[d];
  float tlog = tptr[layer] * LOG2E;
  int slot8 = d >> 3, sub16 = (d & 7) << 4;

  int cur = gw;
  int beg = off[cur];
  int deg = off[cur + 1] - beg;
  int b = 0;
  if (deg > 0) {
    int s0 = csr_src[beg + min(d, min(deg, CHUNK) - 1)];
    STAGE_NODE(s0, beg, deg, 0);
  }
  float zncur = __half2float(zin[((size_t)cur << 6) + d]);
  int nxt = cur + TW;
  int begN = 0, degN = 0, srcN = 0;
  if (nxt < N) {
    begN = off[nxt];
    degN = off[nxt + 1] - begN;
    if (degN > 0) srcN = csr_src[begN + min(d, min(degN, CHUNK) - 1)];
  }

  while (true) {
    asm volatile("s_waitcnt vmcnt(0)" ::: "memory");
    bool more = (nxt < N);
    int nxt2 = nxt + TW;
    int beg2 = 0, deg2 = 0;
    if (more && nxt2 < N) {
      beg2 = off[nxt2];
      deg2 = off[nxt2 + 1] - beg2;
    }
    if (more && degN > 0) STAGE_NODE(srcN, begN, degN, b ^ 1);
    int src2 = 0;
    if (more && nxt2 < N && deg2 > 0) src2 = csr_src[beg2 + min(d, min(deg2, CHUNK) - 1)];
    float znN = more ? __half2float(zin[((size_t)nxt << 6) + d]) : 0.f;
    float m = -__builtin_inff(), s = 0.f, w = 0.f;
    {
      const __half* zc = &zst[wv][b][0];
      const __half* ec = &efst[wv][b][0];
      int remc = min(CHUNK, deg);
      for (int eo = 0; eo < remc; eo += 4) {
        int r4 = remc - eo;
        BATCH4(zc, ec, eo, r4);
      }
      for (int base = CHUNK; base < deg; base += CHUNK) {
        int rem = min(CHUNK, deg - base);
        int e0 = beg + base;
        int sT = csr_src[e0 + min(d, rem - 1)];
        STAGE_NODE(sT, e0, rem, b);
        asm volatile("s_waitcnt vmcnt(0)" ::: "memory");
        for (int eo = 0; eo < rem; eo += 4) {
          int r4 = rem - eo;
          BATCH4(zc, ec, eo, r4);
        }
      }
    }
    float outd = w / (s + 1e-16f) + zncur;  // empty segment -> zn
    aggh[((size_t)cur << 6) + d] = __float2half(outd);
    if (!more) break;
    cur = nxt; beg = begN; deg = degN; zncur = znN;
    nxt = nxt2; begN = beg2; degN = deg2; srcN = src2;
    b ^= 1;
  }
}

// MLP: grid-stride tiles of 32 nodes (8/wave); weights fp16 in LDS [red][out];
// fdot2 (fp32-accum) GEMMs; fp16 activations staged by one global_load_lds per wave.
template <int RESID, int LASTL>
__global__ void mlp_kernel(const __half* __restrict__ aggh, float* __restrict__ hbuf,
                           __half* __restrict__ zout, const __half2* __restrict__ w1p,
                           const __half2* __restrict__ w2p, const float* __restrict__ b1,
                           const float* __restrict__ g1, const float* __restrict__ bb1,
                           const float* __restrict__ b2, const float* __restrict__ nlg,
                           const float* __restrict__ nlb, int N, int ntiles) {
  __shared__ __align__(16) h2 w1s[32 * 128];  // 16 KB [g][j]
  __shared__ __align__(16) h2 w2s[64 * 64];   // 16 KB [g][j]
  __shared__ __align__(16) h2 zs[4][512];     // 2 KB/wave
  int wv = threadIdx.x >> 6, d = threadIdx.x & 63;
  {
    const char* gp1 = (const char*)w1p;
    const char* gp2 = (const char*)w2p;
    for (int i = wv; i < 16; i += 4) {
      gload_lds16(gp1 + (i << 10) + (d << 4), (char*)w1s + (i << 10));
      gload_lds16(gp2 + (i << 10) + (d << 4), (char*)w2s + (i << 10));
    }
  }
  asm volatile("s_waitcnt vmcnt(0)" ::: "memory");
  __syncthreads();
  float bb0 = b1[d], bb64 = b1[64 + d];
  float g1d = g1[d], g1d64 = g1[64 + d], bb1d = bb1[d], bb1d64 = bb1[64 + d];
  float b2d = b2[d];
  float g0 = nlg[d], bb = nlb[d];
  const float4* af4 = reinterpret_cast<const float4*>(&zs[wv][0]);
  __half* zhp = reinterpret_cast<__half*>(&zs[wv][0]);

  for (int tile = blockIdx.x; tile < ntiles; tile += gridDim.x) {
    int n0 = tile * 32 + wv * 8;
    if (n0 >= N) continue;
    asm volatile("s_waitcnt lgkmcnt(0)" ::: "memory");
    gload_lds16((const char*)(aggh + ((size_t)n0 << 6)) + (d << 4), (char*)&zs[wv][0]);
    asm volatile("s_waitcnt vmcnt(0)" ::: "memory");
    float y0[MTILE], y1[MTILE];
#pragma unroll
    for (int j = 0; j < MTILE; ++j) { y0[j] = bb0; y1[j] = bb64; }
    for (int ii = 0; ii < 8; ++ii) {
      h2 wA0 = w1s[(4 * ii + 0) * 128 + d], wA1 = w1s[(4 * ii + 1) * 128 + d];
      h2 wA2 = w1s[(4 * ii + 2) * 128 + d], wA3 = w1s[(4 * ii + 3) * 128 + d];
      h2 wB0 = w1s[(4 * ii + 0) * 128 + 64 + d], wB1 = w1s[(4 * ii + 1) * 128 + 64 + d];
      h2 wB2 = w1s[(4 * ii + 2) * 128 + 64 + d], wB3 = w1s[(4 * ii + 3) * 128 + 64 + d];
#pragma unroll
      for (int j = 0; j < MTILE; ++j) {
        float4 av = af4[j * 8 + ii];
        h2 a0 = __builtin_bit_cast(h2, av.x), a1 = __builtin_bit_cast(h2, av.y);
        h2 a2 = __builtin_bit_cast(h2, av.z), a3 = __builtin_bit_cast(h2, av.w);
        y0[j] = fdot2f(a3, wA3, fdot2f(a2, wA2, fdot2f(a1, wA1, fdot2f(a0, wA0, y0[j]))));
        y1[j] = fdot2f(a3, wB3, fdot2f(a2, wB2, fdot2f(a1, wB1, fdot2f(a0, wB0, y1[j]))));
      }
    }
    for (int j = 0; j < MTILE; ++j) {
      float mu = wred(y0[j] + y1[j]) * (1.f / 128.f);
      float d0 = y0[j] - mu, d1 = y1[j] - mu;
      float var = wred(d0 * d0 + d1 * d1) * (1.f / 128.f);
      float r = rsqrtf(var + 1e-5f);
      float z0 = fmaxf(d0 * r * g1d + bb1d, 0.f);
      float z1 = fmaxf(d1 * r * g1d64 + bb1d64, 0.f);
      zhp[j * 128 + d] = __float2half(z0);
      zhp[j * 128 + 64 + d] = __float2half(z1);
    }
    float o2[MTILE];
#pragma unroll
    for (int j = 0; j < MTILE; ++j) o2[j] = b2d;
    for (int ii = 0; ii < 16; ++ii) {
      h2 w0 = w2s[(4 * ii + 0) * 64 + d], w1v = w2s[(4 * ii + 1) * 64 + d];
      h2 w2v = w2s[(4 * ii + 2) * 64 + d], w3 = w2s[(4 * ii + 3) * 64 + d];
#pragma unroll
      for (int j = 0; j < MTILE; ++j) {
        float4 zv = af4[j * 16 + ii];
        h2 z0 = __builtin_bit_cast(h2, zv.x), z1 = __builtin_bit_cast(h2, zv.y);
        h2 z2 = __builtin_bit_cast(h2, zv.z), z3 = __builtin_bit_cast(h2, zv.w);
        o2[j] = fdot2f(z3, w3, fdot2f(z2, w2v, fdot2f(z1, w1v, fdot2f(z0, w0, o2[j]))));
      }
    }
    for (int j = 0; j < MTILE; ++j) {
      int n = n0 + j;
      if (n >= N) break;
      float hb = RESID ? hbuf[((size_t)n << 6) + d] : 0.f;
      float hnew = hb + o2[j];
      if (!LASTL) hbuf[((size_t)n << 6) + d] = hnew;
      float mu = wred(hnew) * (1.f / 64.f);
      float dd2 = hnew - mu;
      float var = wred(dd2 * dd2) * (1.f / 64.f);
      float r2 = rsqrtf(var + 1e-5f);
      zout[((size_t)n << 6) + d] = __float2half(fmaxf(dd2 * r2 * g0 + bb, 0.f));
    }
  }
}

// out = z @ lin_W + lin_b; MTILE nodes/wave, lin weights staged in LDS (fp16 packed).
__global__ void final_kernel(const __half* __restrict__ zh, const __half2* __restrict__ linp,
                             const float* __restrict__ linb, float* __restrict__ out, int N) {
  __shared__ __align__(16) __half2 lins[32 * 112 + 32];
  __shared__ __half zsh[4][MTILE * 64];
  int wv = threadIdx.x >> 6, d = threadIdx.x & 63;
  {
    const char* gp = (const char*)linp;
    for (int i = wv; i < 14; i += 4)
      gload_lds16(gp + (i << 10) + (d << 4), (char*)lins + (i << 10));
  }
  asm volatile("s_waitcnt vmcnt(0)" ::: "memory");
  __syncthreads();
  int n0 = (blockIdx.x * 4 + wv) * MTILE;
  if (n0 >= N) return;
  for (int j = 0; j < MTILE; ++j) {
    int n = min(n0 + j, N - 1);
    zsh[wv][j * 64 + d] = zh[((size_t)n << 6) + d];
  }
  float a0[MTILE], a1[MTILE];
  float lb0 = linb[d];
  float lb1 = (d < 48) ? linb[64 + d] : 0.f;
#pragma unroll
  for (int j = 0; j < MTILE; ++j) { a0[j] = lb0; a1[j] = lb1; }
  for (int g = 0; g < 32; ++g) {
    float2 w0 = __half22float2(lins[g * 112 + d]);
    float2 w1 = __half22float2(lins[g * 112 + 64 + d]);  // d>=48 reads pad, unused
#pragma unroll
    for (int j = 0; j < MTILE; ++j) {
      float2 zz = __half22float2(*reinterpret_cast<const __half2*>(&zsh[wv][j * 64 + 2 * g]));
      a0[j] = fmaf(zz.x, w0.x, a0[j]); a0[j] = fmaf(zz.y, w0.y, a0[j]);
      a1[j] = fmaf(zz.x, w1.x, a1[j]); a1[j] = fmaf(zz.y, w1.y, a1[j]);
    }
  }
  for (int j = 0; j < MTILE; ++j) {
    int n = n0 + j;
    if (n >= N) break;
    size_t b = (size_t)n * 112;
    out[b + d] = a0[j];
    if (d < 48) out[b + 64 + d] = a1[j];
  }
}

extern "C" void kernel_launch(void* const* d_in, const int* in_sizes, int n_in, void* d_out,
                              int out_size, void* d_ws, size_t ws_size, hipStream_t stream) {
  const float* x = (const float*)d_in[0];
  const float* eattr = (const float*)d_in[1];
  const int* ei = (const int*)d_in[2];
  const float* node_W = (const float*)d_in[3];
  const float* node_b = (const float*)d_in[4];
  const float* edge_W = (const float*)d_in[5];
  const float* edge_b = (const float*)d_in[6];
  const float* tptr = (const float*)d_in[7];
  const float* W1 = (const float*)d_in[8];
  const float* b1 = (const float*)d_in[9];
  const float* g1 = (const float*)d_in[10];
  const float* bb1 = (const float*)d_in[11];
  const float* W2 = (const float*)d_in[12];
  const float* b2 = (const float*)d_in[13];
  const float* lng = (const float*)d_in[14];
  const float* lnb = (const float*)d_in[15];
  const float* linW = (const float*)d_in[16];
  const float* linb = (const float*)d_in[17];
  const int N = in_sizes[0] / 8;
  const int E = in_sizes[1] / 8;
  const int* srcp = ei;
  const int* dstp = ei + E;

  char* ws = (char*)d_ws;
  size_t o = 0;
  auto alloc = [&](size_t bytes) {
    void* p = ws + o;
    o += (bytes + 255) & ~(size_t)255;
    return p;
  };
  const int nb = (N + 1023) / 1024;
  int* off = (int*)alloc((size_t)(N + 1) * 4);
  int* cnt = (int*)alloc((size_t)N * 4);
  int* bsum = (int*)alloc((size_t)nb * 4);
  int* boff = (int*)alloc((size_t)(nb + 1) * 4);
  int* csr_src = (int*)alloc((size_t)E * 4);
  __half* zh0 = (__half*)alloc((size_t)N * 64 * 2);
  __half* zh1 = (__half*)alloc((size_t)N * 64 * 2);
  __half* aggh = (__half*)alloc((size_t)N * 64 * 2 + 2048);  // slack for mlp stage over-read
  float* hbuf = (float*)alloc((size_t)N * 64 * 4);
  __half2* w1p = (__half2*)alloc((size_t)5 * 4096 * 4);
  __half2* w2p = (__half2*)alloc((size_t)5 * 4096 * 4);
  __half2* linp = (__half2*)alloc((size_t)32 * 112 * 4 + 256);
  __half* ecsr = (__half*)alloc((size_t)E * 16 + 2048);  // fp16 CSR rows + staging slack

  int nbm = (N + 4 * MTILE - 1) / (4 * MTILE);
  int ntiles = (N + 31) / 32;
  int TW = AGG_BLOCKS * WPB;

  node_enc_kernel<<<(N * 64 + 255) / 256, 256, 0, stream>>>(x, node_W, node_b, zh0, N);
  wprep_kernel<<<(2 * 5 * 4096 + 32 * 112 + 255) / 256, 256, 0, stream>>>(W1, W2, linW, w1p,
                                                                          w2p, linp);
  hipMemsetAsync(cnt, 0, (size_t)N * 4, stream);
  hist_kernel<<<(E + 255) / 256, 256, 0, stream>>>(dstp, cnt, E);
  scanA_kernel<<<nb, 1024, 0, stream>>>(cnt, off, bsum, N);
  scanB_kernel<<<1, 64, 0, stream>>>(bsum, boff, nb);
  scanC_kernel<<<(N + 1 + 255) / 256, 256, 0, stream>>>(off, boff, N, nb);
  hipMemsetAsync(cnt, 0, (size_t)N * 4, stream);
  scatter_kernel<<<(E + 255) / 256, 256, 0, stream>>>(srcp, dstp, off, cnt, csr_src, eattr,
                                                      ecsr, E);

  const __half* zi[5] = {zh0, zh1, zh0, zh1, zh0};
  __half* zo[5] = {zh1, zh0, zh1, zh0, zh1};
#define LAYER(RES, LAST, l, NL)                                                             \
  do {                                                                                      \
    agg_kernel<<<AGG_BLOCKS, 256, 0, stream>>>(zi[l], aggh, off, csr_src, ecsr, edge_W,     \
                                               edge_b, tptr, l, N, TW);                     \
    mlp_kernel<RES, LAST><<<MLP_BLOCKS, 256, 0, stream>>>(                                  \
        aggh, hbuf, zo[l], w1p + (l)*4096, w2p + (l)*4096, b1 + (l)*128, g1 + (l)*128,      \
        bb1 + (l)*128, b2 + (l)*64, lng + (NL)*64, lnb + (NL)*64, N, ntiles);               \
  } while (0)

  LAYER(0, 0, 0, 1);
  LAYER(1, 0, 1, 2);
  LAYER(1, 0, 2, 3);
  LAYER(1, 0, 3, 4);
  LAYER(1, 1, 4, 0);  // last layer applies layer-0 norm for the head
  final_kernel<<<nbm, 256, 0, stream>>>(zo[4], linp, linb, (float*)d_out, N);
}

// Round 18
// 590.446 us; speedup vs baseline: 1.1161x; 1.1161x over previous
//
#include <hip/hip_runtime.h>
#include <hip/hip_fp16.h>

#define WPB 4     // waves per block in agg
#define CHUNK 32  // edges staged per buffer
#define MTILE 8   // nodes per wave in mlp/final
#define AGG_BLOCKS 1024
#define MLP_BLOCKS 1024

typedef _Float16 h2 __attribute__((ext_vector_type(2)));

static __device__ __forceinline__ float fdot2f(h2 a, h2 b, float c) {
#if __has_builtin(__builtin_amdgcn_fdot2)
  return __builtin_amdgcn_fdot2(a, b, c, false);
#else
  return c + (float)a[0] * (float)b[0] + (float)a[1] * (float)b[1];
#endif
}

static __device__ __forceinline__ void gload_lds16(const void* gp, void* lp) {
  __builtin_amdgcn_global_load_lds((const __attribute__((address_space(1))) void*)gp,
                                   (__attribute__((address_space(3))) void*)lp, 16, 0, 0);
}

static __device__ __forceinline__ float wred(float v) {
#pragma unroll
  for (int o = 32; o > 0; o >>= 1) v += __shfl_xor(v, o, 64);
  return v;
}

// h0[n,d] = x[n,:8] @ node_W[:,d] + node_b[d], stored fp16
__global__ void node_enc_kernel(const float* __restrict__ x, const float* __restrict__ W,
                                const float* __restrict__ b, __half* __restrict__ z, int N) {
  int t = blockIdx.x * blockDim.x + threadIdx.x;
  if (t >= N * 64) return;
  int n = t >> 6, d = t & 63;
  float acc = b[d];
#pragma unroll
  for (int k = 0; k < 8; ++k) acc = fmaf(x[n * 8 + k], W[k * 64 + d], acc);
  z[t] = __float2half(acc);
}

__global__ void hist_kernel(const int* __restrict__ dst, int* __restrict__ cnt, int E) {
  int e = blockIdx.x * blockDim.x + threadIdx.x;
  if (e < E) atomicAdd(&cnt[dst[e]], 1);
}

// --- multi-block exclusive scan of cnt[0..n) -> off[0..n] ---
__global__ void scanA_kernel(const int* __restrict__ cnt, int* __restrict__ off,
                             int* __restrict__ bsum, int n) {
  __shared__ int lds[1024];
  int tid = threadIdx.x;
  int i = blockIdx.x * 1024 + tid;
  int v = (i < n) ? cnt[i] : 0;
  lds[tid] = v;
  __syncthreads();
  for (int ofs = 1; ofs < 1024; ofs <<= 1) {
    int tv = (tid >= ofs) ? lds[tid - ofs] : 0;
    __syncthreads();
    lds[tid] += tv;
    __syncthreads();
  }
  if (i < n) off[i] = lds[tid] - v;  // local exclusive
  if (tid == 1023) bsum[blockIdx.x] = lds[1023];
}

__global__ void scanB_kernel(const int* __restrict__ bsum, int* __restrict__ boff, int nb) {
  if (threadIdx.x == 0) {
    int acc = 0;
    for (int i = 0; i < nb; ++i) {
      boff[i] = acc;
      acc += bsum[i];
    }
    boff[nb] = acc;
  }
}

__global__ void scanC_kernel(int* __restrict__ off, const int* __restrict__ boff, int n, int nb) {
  int i = blockIdx.x * blockDim.x + threadIdx.x;
  if (i < n)
    off[i] += boff[i >> 10];
  else if (i == n)
    off[n] = boff[nb];
}

// scatter src ids + fp16 edge features (16B rows) into CSR order.
__global__ void scatter_kernel(const int* __restrict__ src, const int* __restrict__ dst,
                               const int* __restrict__ off, int* __restrict__ cur,
                               int* __restrict__ csr_src, const float* __restrict__ edge_attr,
                               __half* __restrict__ ecsr, int E) {
  int e = blockIdx.x * blockDim.x + threadIdx.x;
  if (e >= E) return;
  int dn = dst[e];
  int p = atomicAdd(&cur[dn], 1);
  int idx = off[dn] + p;
  csr_src[idx] = src[e];
  const float4* ap = reinterpret_cast<const float4*>(edge_attr + (size_t)e * 8);
  float4 a0 = ap[0], a1 = ap[1];
  __half2 q0 = __floats2half2_rn(a0.x, a0.y);
  __half2 q1 = __floats2half2_rn(a0.z, a0.w);
  __half2 q2 = __floats2half2_rn(a1.x, a1.y);
  __half2 q3 = __floats2half2_rn(a1.z, a1.w);
  uint4 row;
  row.x = __builtin_bit_cast(unsigned int, q0);
  row.y = __builtin_bit_cast(unsigned int, q1);
  row.z = __builtin_bit_cast(unsigned int, q2);
  row.w = __builtin_bit_cast(unsigned int, q3);
  *reinterpret_cast<uint4*>(ecsr + (size_t)idx * 8) = row;
}

// Pack weights to fp16 half2 pairs along the reduction dim in [red][out] orientation:
//   w1p[l][g=0..31][j=0..127] = (W1[2g][j], W1[2g+1][j])
//   w2p[l][g=0..63][j=0..63]  = (W2[2g][j], W2[2g+1][j])
//   linp[g=0..31][o=0..111]   = (linW[2g][o], linW[2g+1][o])
__global__ void wprep_kernel(const float* __restrict__ W1, const float* __restrict__ W2,
                             const float* __restrict__ linW, __half2* __restrict__ w1p,
                             __half2* __restrict__ w2p, __half2* __restrict__ linp) {
  int t = blockIdx.x * blockDim.x + threadIdx.x;
  const int tot1 = 5 * 32 * 128;
  if (t < tot1) {
    int l = t / 4096, r = t % 4096;
    int g = r / 128, j = r % 128;
    const float* base = W1 + l * 8192;
    w1p[t] = __floats2half2_rn(base[(2 * g) * 128 + j], base[(2 * g + 1) * 128 + j]);
  } else if (t < 2 * tot1) {
    int u = t - tot1;
    int l = u / 4096, r = u % 4096;
    int g = r / 64, j = r % 64;
    const float* base = W2 + l * 8192;
    w2p[u] = __floats2half2_rn(base[(2 * g) * 64 + j], base[(2 * g + 1) * 64 + j]);
  } else if (t < 2 * tot1 + 32 * 112) {
    int u = t - 2 * tot1;
    int g = u / 112, o = u % 112;
    linp[u] = __floats2half2_rn(linW[(2 * g) * 112 + o], linW[(2 * g + 1) * 112 + o]);
  }
}

#define EAH(R)                                                                     \
  fdot2f(__builtin_bit_cast(h2, (R).w), eWh[3],                                    \
         fdot2f(__builtin_bit_cast(h2, (R).z), eWh[2],                             \
                fdot2f(__builtin_bit_cast(h2, (R).y), eWh[1],                      \
                       fdot2f(__builtin_bit_cast(h2, (R).x), eWh[0], ebd))))

#define BATCH4(ZP, EH, EO, R4)                                                   \
  {                                                                              \
    float z0 = __half2float(ZP[(EO + 0) * 64 + d]);                              \
    float z1 = __half2float(ZP[(EO + 1) * 64 + d]);                              \
    float z2 = __half2float(ZP[(EO + 2) * 64 + d]);                              \
    float z3 = __half2float(ZP[(EO + 3) * 64 + d]);                              \
    const float4* fp4 = reinterpret_cast<const float4*>(EH + (size_t)(EO)*8);    \
    float4 r0 = fp4[0], r1 = fp4[1], r2 = fp4[2], r3 = fp4[3];                   \
    float ea0 = EAH(r0), ea1 = EAH(r1), ea2 = EAH(r2), ea3 = EAH(r3);            \
    float ms0 = fmaxf(z0 + ea0, 0.f) + 1e-7f;                                    \
    float ms1 = fmaxf(z1 + ea1, 0.f) + 1e-7f;                                    \
    float ms2 = fmaxf(z2 + ea2, 0.f) + 1e-7f;                                    \
    float ms3 = fmaxf(z3 + ea3, 0.f) + 1e-7f;                                    \
    float l0 = ms0 * tval, l1 = ms1 * tval, l2 = ms2 * tval, l3 = ms3 * tval;    \
    if (R4 < 4) {                                                                \
      if (R4 < 2) l1 = -__builtin_inff();                                        \
      if (R4 < 3) l2 = -__builtin_inff();                                        \
      l3 = -__builtin_inff();                                                    \
    }                                                                            \
    float bm = fmaxf(fmaxf(l0, l1), fmaxf(l2, l3));                              \
    float nm = fmaxf(m, bm);                                                     \
    float sc = __expf(m - nm);                                                   \
    float p0 = __expf(l0 - nm), p1 = __expf(l1 - nm);                            \
    float p2 = __expf(l2 - nm), p3 = __expf(l3 - nm);                            \
    s = fmaf(s, sc, (p0 + p1) + (p2 + p3));                                      \
    w = fmaf(w, sc, fmaf(p0, ms0, p1 * ms1) + fmaf(p2, ms2, p3 * ms3));          \
    m = nm;                                                                      \
  }

#define STAGE_NODE(SRCREG, BEGV, DEGV, BUF)                                           \
  {                                                                                   \
    int rem_ = min(CHUNK, DEGV);                                                      \
    int n8_ = (rem_ + 7) >> 3;                                                        \
    char* zb_ = (char*)&zst[wv][BUF][0];                                              \
    for (int p_ = 0; p_ < n8_; ++p_) {                                                \
      int sl_ = min((p_ << 3) + slot8, rem_ - 1);                                     \
      int sn_ = __shfl(SRCREG, sl_);                                                  \
      gload_lds16((const char*)(zin + ((size_t)sn_ << 6)) + sub16, zb_ + (p_ << 10)); \
    }                                                                                 \
    gload_lds16((const char*)ef + ((size_t)(BEGV) + min(d, rem_ - 1)) * 16,           \
                (char*)&efst[wv][BUF][0]);                                            \
  }

// One wave handles nodes gw, gw+TW, ... with a 2-deep cross-node staging pipeline.
__global__ void agg_kernel(const __half* __restrict__ zin, __half* __restrict__ aggh,
                           const int* __restrict__ off, const int* __restrict__ csr_src,
                           const __half* __restrict__ ef, const float* __restrict__ edge_W,
                           const float* __restrict__ edge_b, const float* __restrict__ tptr,
                           int layer, int N, int TW) {
  __shared__ __align__(16) __half zst[WPB][2][CHUNK * 64];  // 2 x 4 KB per wave
  __shared__ __align__(16) __half efst[WPB][2][64 * 8];     // 2 x 1 KB per wave (fp16 rows)
  int wv = threadIdx.x >> 6, d = threadIdx.x & 63;
  int gw = blockIdx.x * WPB + wv;
  if (gw >= N) return;
  h2 eWh[4];
#pragma unroll
  for (int q = 0; q < 4; ++q) {
    __half2 hp = __floats2half2_rn(edge_W[(2 * q) * 64 + d], edge_W[(2 * q + 1) * 64 + d]);
    eWh[q] = __builtin_bit_cast(h2, hp);
  }
  float ebd = edge_b[d];
  float tval = tptr[layer];
  int slot8 = d >> 3, sub16 = (d & 7) << 4;

  int cur = gw;
  int beg = off[cur];
  int deg = off[cur + 1] - beg;
  int b = 0;
  if (deg > 0) {
    int s0 = csr_src[beg + min(d, min(deg, 64) - 1)];
    STAGE_NODE(s0, beg, deg, 0);
  }
  float zncur = __half2float(zin[((size_t)cur << 6) + d]);
  int nxt = cur + TW;
  int begN = 0, degN = 0, srcN = 0;
  if (nxt < N) {
    begN = off[nxt];
    degN = off[nxt + 1] - begN;
    if (degN > 0) srcN = csr_src[begN + min(d, min(degN, 64) - 1)];
  }

  while (true) {
    asm volatile("s_waitcnt vmcnt(0)" ::: "memory");
    bool more = (nxt < N);
    int nxt2 = nxt + TW;
    int beg2 = 0, deg2 = 0;
    if (more && nxt2 < N) {
      beg2 = off[nxt2];
      deg2 = off[nxt2 + 1] - beg2;
    }
    if (more && degN > 0) STAGE_NODE(srcN, begN, degN, b ^ 1);
    int src2 = 0;
    if (more && nxt2 < N && deg2 > 0) src2 = csr_src[beg2 + min(d, min(deg2, 64) - 1)];
    float znN = more ? __half2float(zin[((size_t)nxt << 6) + d]) : 0.f;
    float m = -__builtin_inff(), s = 0.f, w = 0.f;
    {
      const __half* zc = &zst[wv][b][0];
      const __half* ec = &efst[wv][b][0];
      int remc = min(CHUNK, deg);
      for (int eo = 0; eo < remc; eo += 4) {
        int r4 = remc - eo;
        BATCH4(zc, ec, eo, r4);
      }
      for (int base = CHUNK; base < deg; base += CHUNK) {
        int rem = min(CHUNK, deg - base);
        int e0 = beg + base;
        int sT = csr_src[e0 + min(d, rem - 1)];
        STAGE_NODE(sT, e0, rem, b);
        asm volatile("s_waitcnt vmcnt(0)" ::: "memory");
        for (int eo = 0; eo < rem; eo += 4) {
          int r4 = rem - eo;
          BATCH4(zc, ec, eo, r4);
        }
      }
    }
    float outd = w / (s + 1e-16f) + zncur;  // empty segment -> zn
    aggh[((size_t)cur << 6) + d] = __float2half(outd);
    if (!more) break;
    cur = nxt; beg = begN; deg = degN; zncur = znN;
    nxt = nxt2; begN = beg2; degN = deg2; srcN = src2;
    b ^= 1;
  }
}

// MLP: grid-stride tiles of 32 nodes (8/wave); weights fp16 in LDS [red][out];
// fdot2 (fp32-accum) GEMMs; fp16 activations staged by one global_load_lds per wave.
template <int RESID, int LASTL>
__global__ void mlp_kernel(const __half* __restrict__ aggh, float* __restrict__ hbuf,
                           __half* __restrict__ zout, const __half2* __restrict__ w1p,
                           const __half2* __restrict__ w2p, const float* __restrict__ b1,
                           const float* __restrict__ g1, const float* __restrict__ bb1,
                           const float* __restrict__ b2, const float* __restrict__ nlg,
                           const float* __restrict__ nlb, int N, int ntiles) {
  __shared__ __align__(16) h2 w1s[32 * 128];  // 16 KB [g][j]
  __shared__ __align__(16) h2 w2s[64 * 64];   // 16 KB [g][j]
  __shared__ __align__(16) h2 zs[4][512];     // 2 KB/wave
  int wv = threadIdx.x >> 6, d = threadIdx.x & 63;
  {
    const char* gp1 = (const char*)w1p;
    const char* gp2 = (const char*)w2p;
    for (int i = wv; i < 16; i += 4) {
      gload_lds16(gp1 + (i << 10) + (d << 4), (char*)w1s + (i << 10));
      gload_lds16(gp2 + (i << 10) + (d << 4), (char*)w2s + (i << 10));
    }
  }
  asm volatile("s_waitcnt vmcnt(0)" ::: "memory");
  __syncthreads();
  float bb0 = b1[d], bb64 = b1[64 + d];
  float g1d = g1[d], g1d64 = g1[64 + d], bb1d = bb1[d], bb1d64 = bb1[64 + d];
  float b2d = b2[d];
  float g0 = nlg[d], bb = nlb[d];
  const float4* af4 = reinterpret_cast<const float4*>(&zs[wv][0]);
  __half* zhp = reinterpret_cast<__half*>(&zs[wv][0]);

  for (int tile = blockIdx.x; tile < ntiles; tile += gridDim.x) {
    int n0 = tile * 32 + wv * 8;
    if (n0 >= N) continue;
    asm volatile("s_waitcnt lgkmcnt(0)" ::: "memory");  // prior tile's z reads done
    gload_lds16((const char*)(aggh + ((size_t)n0 << 6)) + (d << 4), (char*)&zs[wv][0]);
    asm volatile("s_waitcnt vmcnt(0)" ::: "memory");
    float y0[MTILE], y1[MTILE];
#pragma unroll
    for (int j = 0; j < MTILE; ++j) { y0[j] = bb0; y1[j] = bb64; }
    // GEMM1: 8 iters x 8 dd (4 h2-pairs)
    for (int ii = 0; ii < 8; ++ii) {
      h2 wA0 = w1s[(4 * ii + 0) * 128 + d], wA1 = w1s[(4 * ii + 1) * 128 + d];
      h2 wA2 = w1s[(4 * ii + 2) * 128 + d], wA3 = w1s[(4 * ii + 3) * 128 + d];
      h2 wB0 = w1s[(4 * ii + 0) * 128 + 64 + d], wB1 = w1s[(4 * ii + 1) * 128 + 64 + d];
      h2 wB2 = w1s[(4 * ii + 2) * 128 + 64 + d], wB3 = w1s[(4 * ii + 3) * 128 + 64 + d];
#pragma unroll
      for (int j = 0; j < MTILE; ++j) {
        float4 av = af4[j * 8 + ii];  // broadcast 8 halves of a[j]
        h2 a0 = __builtin_bit_cast(h2, av.x), a1 = __builtin_bit_cast(h2, av.y);
        h2 a2 = __builtin_bit_cast(h2, av.z), a3 = __builtin_bit_cast(h2, av.w);
        y0[j] = fdot2f(a3, wA3, fdot2f(a2, wA2, fdot2f(a1, wA1, fdot2f(a0, wA0, y0[j]))));
        y1[j] = fdot2f(a3, wB3, fdot2f(a2, wB2, fdot2f(a1, wB1, fdot2f(a0, wB0, y1[j]))));
      }
    }
    // LN128 + relu -> z (fp16, overwrites a region; a is dead)
    for (int j = 0; j < MTILE; ++j) {
      float mu = wred(y0[j] + y1[j]) * (1.f / 128.f);
      float d0 = y0[j] - mu, d1 = y1[j] - mu;
      float var = wred(d0 * d0 + d1 * d1) * (1.f / 128.f);
      float r = rsqrtf(var + 1e-5f);
      float z0 = fmaxf(d0 * r * g1d + bb1d, 0.f);
      float z1 = fmaxf(d1 * r * g1d64 + bb1d64, 0.f);
      zhp[j * 128 + d] = __float2half(z0);
      zhp[j * 128 + 64 + d] = __float2half(z1);
    }
    // GEMM2: 16 iters x 8 k
    float o2[MTILE];
#pragma unroll
    for (int j = 0; j < MTILE; ++j) o2[j] = b2d;
    for (int ii = 0; ii < 16; ++ii) {
      h2 w0 = w2s[(4 * ii + 0) * 64 + d], w1v = w2s[(4 * ii + 1) * 64 + d];
      h2 w2v = w2s[(4 * ii + 2) * 64 + d], w3 = w2s[(4 * ii + 3) * 64 + d];
#pragma unroll
      for (int j = 0; j < MTILE; ++j) {
        float4 zv = af4[j * 16 + ii];
        h2 z0 = __builtin_bit_cast(h2, zv.x), z1 = __builtin_bit_cast(h2, zv.y);
        h2 z2 = __builtin_bit_cast(h2, zv.z), z3 = __builtin_bit_cast(h2, zv.w);
        o2[j] = fdot2f(z3, w3, fdot2f(z2, w2v, fdot2f(z1, w1v, fdot2f(z0, w0, o2[j]))));
      }
    }
    for (int j = 0; j < MTILE; ++j) {
      int n = n0 + j;
      if (n >= N) break;
      float hb = RESID ? hbuf[((size_t)n << 6) + d] : 0.f;
      float hnew = hb + o2[j];
      if (!LASTL) hbuf[((size_t)n << 6) + d] = hnew;
      float mu = wred(hnew) * (1.f / 64.f);
      float dd2 = hnew - mu;
      float var = wred(dd2 * dd2) * (1.f / 64.f);
      float r2 = rsqrtf(var + 1e-5f);
      zout[((size_t)n << 6) + d] = __float2half(fmaxf(dd2 * r2 * g0 + bb, 0.f));
    }
  }
}

// out = z @ lin_W + lin_b; MTILE nodes/wave, lin weights staged in LDS (fp16 packed).
__global__ void final_kernel(const __half* __restrict__ zh, const __half2* __restrict__ linp,
                             const float* __restrict__ linb, float* __restrict__ out, int N) {
  __shared__ __align__(16) __half2 lins[32 * 112 + 32];
  __shared__ __half zsh[4][MTILE * 64];
  int wv = threadIdx.x >> 6, d = threadIdx.x & 63;
  {
    const char* gp = (const char*)linp;
    for (int i = wv; i < 14; i += 4)
      gload_lds16(gp + (i << 10) + (d << 4), (char*)lins + (i << 10));
  }
  asm volatile("s_waitcnt vmcnt(0)" ::: "memory");
  __syncthreads();
  int n0 = (blockIdx.x * 4 + wv) * MTILE;
  if (n0 >= N) return;
  for (int j = 0; j < MTILE; ++j) {
    int n = min(n0 + j, N - 1);
    zsh[wv][j * 64 + d] = zh[((size_t)n << 6) + d];
  }
  float a0[MTILE], a1[MTILE];
  float lb0 = linb[d];
  float lb1 = (d < 48) ? linb[64 + d] : 0.f;
#pragma unroll
  for (int j = 0; j < MTILE; ++j) { a0[j] = lb0; a1[j] = lb1; }
  for (int g = 0; g < 32; ++g) {
    float2 w0 = __half22float2(lins[g * 112 + d]);
    float2 w1 = __half22float2(lins[g * 112 + 64 + d]);  // d>=48 reads pad, unused
#pragma unroll
    for (int j = 0; j < MTILE; ++j) {
      float2 zz = __half22float2(*reinterpret_cast<const __half2*>(&zsh[wv][j * 64 + 2 * g]));
      a0[j] = fmaf(zz.x, w0.x, a0[j]); a0[j] = fmaf(zz.y, w0.y, a0[j]);
      a1[j] = fmaf(zz.x, w1.x, a1[j]); a1[j] = fmaf(zz.y, w1.y, a1[j]);
    }
  }
  for (int j = 0; j < MTILE; ++j) {
    int n = n0 + j;
    if (n >= N) break;
    size_t b = (size_t)n * 112;
    out[b + d] = a0[j];
    if (d < 48) out[b + 64 + d] = a1[j];
  }
}

extern "C" void kernel_launch(void* const* d_in, const int* in_sizes, int n_in, void* d_out,
                              int out_size, void* d_ws, size_t ws_size, hipStream_t stream) {
  const float* x = (const float*)d_in[0];
  const float* eattr = (const float*)d_in[1];
  const int* ei = (const int*)d_in[2];
  const float* node_W = (const float*)d_in[3];
  const float* node_b = (const float*)d_in[4];
  const float* edge_W = (const float*)d_in[5];
  const float* edge_b = (const float*)d_in[6];
  const float* tptr = (const float*)d_in[7];
  const float* W1 = (const float*)d_in[8];
  const float* b1 = (const float*)d_in[9];
  const float* g1 = (const float*)d_in[10];
  const float* bb1 = (const float*)d_in[11];
  const float* W2 = (const float*)d_in[12];
  const float* b2 = (const float*)d_in[13];
  const float* lng = (const float*)d_in[14];
  const float* lnb = (const float*)d_in[15];
  const float* linW = (const float*)d_in[16];
  const float* linb = (const float*)d_in[17];
  const int N = in_sizes[0] / 8;
  const int E = in_sizes[1] / 8;
  const int* srcp = ei;
  const int* dstp = ei + E;

  char* ws = (char*)d_ws;
  size_t o = 0;
  auto alloc = [&](size_t bytes) {
    void* p = ws + o;
    o += (bytes + 255) & ~(size_t)255;
    return p;
  };
  const int nb = (N + 1023) / 1024;
  int* off = (int*)alloc((size_t)(N + 1) * 4);
  int* cnt = (int*)alloc((size_t)N * 4);
  int* bsum = (int*)alloc((size_t)nb * 4);
  int* boff = (int*)alloc((size_t)(nb + 1) * 4);
  int* csr_src = (int*)alloc((size_t)E * 4);
  __half* zh0 = (__half*)alloc((size_t)N * 64 * 2);
  __half* zh1 = (__half*)alloc((size_t)N * 64 * 2);
  __half* aggh = (__half*)alloc((size_t)N * 64 * 2 + 2048);  // slack for mlp stage over-read
  float* hbuf = (float*)alloc((size_t)N * 64 * 4);
  __half2* w1p = (__half2*)alloc((size_t)5 * 4096 * 4);
  __half2* w2p = (__half2*)alloc((size_t)5 * 4096 * 4);
  __half2* linp = (__half2*)alloc((size_t)32 * 112 * 4 + 256);
  __half* ecsr = (__half*)alloc((size_t)E * 16 + 2048);  // fp16 rows + staging slack

  int nbm = (N + 4 * MTILE - 1) / (4 * MTILE);
  int ntiles = (N + 31) / 32;
  int TW = AGG_BLOCKS * WPB;

  node_enc_kernel<<<(N * 64 + 255) / 256, 256, 0, stream>>>(x, node_W, node_b, zh0, N);
  wprep_kernel<<<(2 * 5 * 4096 + 32 * 112 + 255) / 256, 256, 0, stream>>>(W1, W2, linW, w1p,
                                                                          w2p, linp);
  hipMemsetAsync(cnt, 0, (size_t)N * 4, stream);
  hist_kernel<<<(E + 255) / 256, 256, 0, stream>>>(dstp, cnt, E);
  scanA_kernel<<<nb, 1024, 0, stream>>>(cnt, off, bsum, N);
  scanB_kernel<<<1, 64, 0, stream>>>(bsum, boff, nb);
  scanC_kernel<<<(N + 1 + 255) / 256, 256, 0, stream>>>(off, boff, N, nb);
  hipMemsetAsync(cnt, 0, (size_t)N * 4, stream);
  scatter_kernel<<<(E + 255) / 256, 256, 0, stream>>>(srcp, dstp, off, cnt, csr_src, eattr,
                                                      ecsr, E);

  const __half* zi[5] = {zh0, zh1, zh0, zh1, zh0};
  __half* zo[5] = {zh1, zh0, zh1, zh0, zh1};
#define LAYER(RES, LAST, l, NL)                                                             \
  do {                                                                                      \
    agg_kernel<<<AGG_BLOCKS, 256, 0, stream>>>(zi[l], aggh, off, csr_src, ecsr, edge_W,     \
                                               edge_b, tptr, l, N, TW);                     \
    mlp_kernel<RES, LAST><<<MLP_BLOCKS, 256, 0, stream>>>(                                  \
        aggh, hbuf, zo[l], w1p + (l)*4096, w2p + (l)*4096, b1 + (l)*128, g1 + (l)*128,      \
        bb1 + (l)*128, b2 + (l)*64, lng + (NL)*64, lnb + (NL)*64, N, ntiles);               \
  } while (0)

  LAYER(0, 0, 0, 1);
  LAYER(1, 0, 1, 2);
  LAYER(1, 0, 2, 3);
  LAYER(1, 0, 3, 4);
  LAYER(1, 1, 4, 0);  // last layer applies layer-0 norm for the head
  final_kernel<<<nbm, 256, 0, stream>>>(zo[4], linp, linb, (float*)d_out, N);
}

// Round 19
// 588.010 us; speedup vs baseline: 1.1207x; 1.0041x over previous
//
#include <hip/hip_runtime.h>
#include <hip/hip_fp16.h>

#define WPB 4     // waves per block in agg
#define CHUNK 32  // edges staged per buffer
#define MTILE 8   // nodes per wave in mlp/final
#define AGG_BLOCKS 1024
#define MLP_BLOCKS 1024

typedef _Float16 h2 __attribute__((ext_vector_type(2)));

static __device__ __forceinline__ float fdot2f(h2 a, h2 b, float c) {
#if __has_builtin(__builtin_amdgcn_fdot2)
  return __builtin_amdgcn_fdot2(a, b, c, false);
#else
  return c + (float)a[0] * (float)b[0] + (float)a[1] * (float)b[1];
#endif
}

static __device__ __forceinline__ void gload_lds16(const void* gp, void* lp) {
  __builtin_amdgcn_global_load_lds((const __attribute__((address_space(1))) void*)gp,
                                   (__attribute__((address_space(3))) void*)lp, 16, 0, 0);
}

static __device__ __forceinline__ float wred(float v) {
#pragma unroll
  for (int o = 32; o > 0; o >>= 1) v += __shfl_xor(v, o, 64);
  return v;
}

// Fused prologue: h0 = x @ node_W + node_b (fp16), zero cnt, and pack weights.
// Extra blocks beyond the node range handle the wprep work.
__global__ void enc_prep_kernel(const float* __restrict__ x, const float* __restrict__ W,
                                const float* __restrict__ b, __half* __restrict__ z,
                                int* __restrict__ cnt, const float* __restrict__ W1,
                                const float* __restrict__ W2, const float* __restrict__ linW,
                                __half2* __restrict__ w1p, __half2* __restrict__ w2p,
                                __half2* __restrict__ linp, int N) {
  int t = blockIdx.x * blockDim.x + threadIdx.x;
  if (t < N) cnt[t] = 0;
  if (t < N * 64) {
    int n = t >> 6, d = t & 63;
    float acc = b[d];
#pragma unroll
    for (int k = 0; k < 8; ++k) acc = fmaf(x[n * 8 + k], W[k * 64 + d], acc);
    z[t] = __float2half(acc);
    return;
  }
  int u0 = t - N * 64;
  const int tot1 = 5 * 32 * 128;
  if (u0 < tot1) {
    int l = u0 / 4096, r = u0 % 4096;
    int g = r / 128, j = r % 128;
    const float* base = W1 + l * 8192;
    w1p[u0] = __floats2half2_rn(base[(2 * g) * 128 + j], base[(2 * g + 1) * 128 + j]);
  } else if (u0 < 2 * tot1) {
    int u = u0 - tot1;
    int l = u / 4096, r = u % 4096;
    int g = r / 64, j = r % 64;
    const float* base = W2 + l * 8192;
    w2p[u] = __floats2half2_rn(base[(2 * g) * 64 + j], base[(2 * g + 1) * 64 + j]);
  } else if (u0 < 2 * tot1 + 32 * 112) {
    int u = u0 - 2 * tot1;
    int g = u / 112, o = u % 112;
    linp[u] = __floats2half2_rn(linW[(2 * g) * 112 + o], linW[(2 * g + 1) * 112 + o]);
  }
}

__global__ void hist_kernel(const int* __restrict__ dst, int* __restrict__ cnt, int E) {
  int e = blockIdx.x * blockDim.x + threadIdx.x;
  if (e < E) atomicAdd(&cnt[dst[e]], 1);
}

// --- multi-block exclusive scan of cnt[0..n) -> off[0..n] ---
__global__ void scanA_kernel(const int* __restrict__ cnt, int* __restrict__ off,
                             int* __restrict__ bsum, int n) {
  __shared__ int lds[1024];
  int tid = threadIdx.x;
  int i = blockIdx.x * 1024 + tid;
  int v = (i < n) ? cnt[i] : 0;
  lds[tid] = v;
  __syncthreads();
  for (int ofs = 1; ofs < 1024; ofs <<= 1) {
    int tv = (tid >= ofs) ? lds[tid - ofs] : 0;
    __syncthreads();
    lds[tid] += tv;
    __syncthreads();
  }
  if (i < n) off[i] = lds[tid] - v;  // local exclusive
  if (tid == 1023) bsum[blockIdx.x] = lds[1023];
}

__global__ void scanB_kernel(const int* __restrict__ bsum, int* __restrict__ boff, int nb) {
  if (threadIdx.x == 0) {
    int acc = 0;
    for (int i = 0; i < nb; ++i) {
      boff[i] = acc;
      acc += bsum[i];
    }
    boff[nb] = acc;
  }
}

// also re-zeroes cnt (scanA already consumed the histogram) for scatter's cursor.
__global__ void scanC_kernel(int* __restrict__ off, const int* __restrict__ boff,
                             int* __restrict__ cnt, int n, int nb) {
  int i = blockIdx.x * blockDim.x + threadIdx.x;
  if (i < n) {
    off[i] += boff[i >> 10];
    cnt[i] = 0;
  } else if (i == n) {
    off[n] = boff[nb];
  }
}

// scatter src ids + fp16 edge features (16B rows) into CSR order.
__global__ void scatter_kernel(const int* __restrict__ src, const int* __restrict__ dst,
                               const int* __restrict__ off, int* __restrict__ cur,
                               int* __restrict__ csr_src, const float* __restrict__ edge_attr,
                               __half* __restrict__ ecsr, int E) {
  int e = blockIdx.x * blockDim.x + threadIdx.x;
  if (e >= E) return;
  int dn = dst[e];
  int p = atomicAdd(&cur[dn], 1);
  int idx = off[dn] + p;
  csr_src[idx] = src[e];
  const float4* ap = reinterpret_cast<const float4*>(edge_attr + (size_t)e * 8);
  float4 a0 = ap[0], a1 = ap[1];
  __half2 q0 = __floats2half2_rn(a0.x, a0.y);
  __half2 q1 = __floats2half2_rn(a0.z, a0.w);
  __half2 q2 = __floats2half2_rn(a1.x, a1.y);
  __half2 q3 = __floats2half2_rn(a1.z, a1.w);
  uint4 row;
  row.x = __builtin_bit_cast(unsigned int, q0);
  row.y = __builtin_bit_cast(unsigned int, q1);
  row.z = __builtin_bit_cast(unsigned int, q2);
  row.w = __builtin_bit_cast(unsigned int, q3);
  *reinterpret_cast<uint4*>(ecsr + (size_t)idx * 8) = row;
}

#define EAH(R)                                                                     \
  fdot2f(__builtin_bit_cast(h2, (R).w), eWh[3],                                    \
         fdot2f(__builtin_bit_cast(h2, (R).z), eWh[2],                             \
                fdot2f(__builtin_bit_cast(h2, (R).y), eWh[1],                      \
                       fdot2f(__builtin_bit_cast(h2, (R).x), eWh[0], ebd))))

#define BATCH4(ZP, EH, EO, R4)                                                   \
  {                                                                              \
    float z0 = __half2float(ZP[(EO + 0) * 64 + d]);                              \
    float z1 = __half2float(ZP[(EO + 1) * 64 + d]);                              \
    float z2 = __half2float(ZP[(EO + 2) * 64 + d]);                              \
    float z3 = __half2float(ZP[(EO + 3) * 64 + d]);                              \
    const float4* fp4 = reinterpret_cast<const float4*>(EH + (size_t)(EO)*8);    \
    float4 r0 = fp4[0], r1 = fp4[1], r2 = fp4[2], r3 = fp4[3];                   \
    float ea0 = EAH(r0), ea1 = EAH(r1), ea2 = EAH(r2), ea3 = EAH(r3);            \
    float ms0 = fmaxf(z0 + ea0, 0.f) + 1e-7f;                                    \
    float ms1 = fmaxf(z1 + ea1, 0.f) + 1e-7f;                                    \
    float ms2 = fmaxf(z2 + ea2, 0.f) + 1e-7f;                                    \
    float ms3 = fmaxf(z3 + ea3, 0.f) + 1e-7f;                                    \
    float l0 = ms0 * tval, l1 = ms1 * tval, l2 = ms2 * tval, l3 = ms3 * tval;    \
    if (R4 < 4) {                                                                \
      if (R4 < 2) l1 = -__builtin_inff();                                        \
      if (R4 < 3) l2 = -__builtin_inff();                                        \
      l3 = -__builtin_inff();                                                    \
    }                                                                            \
    float bm = fmaxf(fmaxf(l0, l1), fmaxf(l2, l3));                              \
    float nm = fmaxf(m, bm);                                                     \
    float sc = __expf(m - nm);                                                   \
    float p0 = __expf(l0 - nm), p1 = __expf(l1 - nm);                            \
    float p2 = __expf(l2 - nm), p3 = __expf(l3 - nm);                            \
    s = fmaf(s, sc, (p0 + p1) + (p2 + p3));                                      \
    w = fmaf(w, sc, fmaf(p0, ms0, p1 * ms1) + fmaf(p2, ms2, p3 * ms3));          \
    m = nm;                                                                      \
  }

#define STAGE_NODE(SRCREG, BEGV, DEGV, BUF)                                           \
  {                                                                                   \
    int rem_ = min(CHUNK, DEGV);                                                      \
    int n8_ = (rem_ + 7) >> 3;                                                        \
    char* zb_ = (char*)&zst[wv][BUF][0];                                              \
    for (int p_ = 0; p_ < n8_; ++p_) {                                                \
      int sl_ = min((p_ << 3) + slot8, rem_ - 1);                                     \
      int sn_ = __shfl(SRCREG, sl_);                                                  \
      gload_lds16((const char*)(zin + ((size_t)sn_ << 6)) + sub16, zb_ + (p_ << 10)); \
    }                                                                                 \
    gload_lds16((const char*)ef + ((size_t)(BEGV) + min(d, rem_ - 1)) * 16,           \
                (char*)&efst[wv][BUF][0]);                                            \
  }

// One wave handles nodes gw, gw+TW, ... with a 2-deep cross-node staging pipeline.
__global__ void agg_kernel(const __half* __restrict__ zin, __half* __restrict__ aggh,
                           const int* __restrict__ off, const int* __restrict__ csr_src,
                           const __half* __restrict__ ef, const float* __restrict__ edge_W,
                           const float* __restrict__ edge_b, const float* __restrict__ tptr,
                           int layer, int N, int TW) {
  __shared__ __align__(16) __half zst[WPB][2][CHUNK * 64];  // 2 x 4 KB per wave
  __shared__ __align__(16) __half efst[WPB][2][64 * 8];     // 2 x 1 KB per wave (fp16 rows)
  int wv = threadIdx.x >> 6, d = threadIdx.x & 63;
  int gw = blockIdx.x * WPB + wv;
  if (gw >= N) return;
  h2 eWh[4];
#pragma unroll
  for (int q = 0; q < 4; ++q) {
    __half2 hp = __floats2half2_rn(edge_W[(2 * q) * 64 + d], edge_W[(2 * q + 1) * 64 + d]);
    eWh[q] = __builtin_bit_cast(h2, hp);
  }
  float ebd = edge_b[d];
  float tval = tptr[layer];
  int slot8 = d >> 3, sub16 = (d & 7) << 4;

  int cur = gw;
  int beg = off[cur];
  int deg = off[cur + 1] - beg;
  int b = 0;
  if (deg > 0) {
    int s0 = csr_src[beg + min(d, min(deg, 64) - 1)];
    STAGE_NODE(s0, beg, deg, 0);
  }
  float zncur = __half2float(zin[((size_t)cur << 6) + d]);
  int nxt = cur + TW;
  int begN = 0, degN = 0, srcN = 0;
  if (nxt < N) {
    begN = off[nxt];
    degN = off[nxt + 1] - begN;
    if (degN > 0) srcN = csr_src[begN + min(d, min(degN, 64) - 1)];
  }

  while (true) {
    asm volatile("s_waitcnt vmcnt(0)" ::: "memory");
    bool more = (nxt < N);
    int nxt2 = nxt + TW;
    int beg2 = 0, deg2 = 0;
    if (more && nxt2 < N) {
      beg2 = off[nxt2];
      deg2 = off[nxt2 + 1] - beg2;
    }
    if (more && degN > 0) STAGE_NODE(srcN, begN, degN, b ^ 1);
    int src2 = 0;
    if (more && nxt2 < N && deg2 > 0) src2 = csr_src[beg2 + min(d, min(deg2, 64) - 1)];
    float znN = more ? __half2float(zin[((size_t)nxt << 6) + d]) : 0.f;
    float m = -__builtin_inff(), s = 0.f, w = 0.f;
    {
      const __half* zc = &zst[wv][b][0];
      const __half* ec = &efst[wv][b][0];
      int remc = min(CHUNK, deg);
      for (int eo = 0; eo < remc; eo += 4) {
        int r4 = remc - eo;
        BATCH4(zc, ec, eo, r4);
      }
      for (int base = CHUNK; base < deg; base += CHUNK) {
        int rem = min(CHUNK, deg - base);
        int e0 = beg + base;
        int sT = csr_src[e0 + min(d, rem - 1)];
        STAGE_NODE(sT, e0, rem, b);
        asm volatile("s_waitcnt vmcnt(0)" ::: "memory");
        for (int eo = 0; eo < rem; eo += 4) {
          int r4 = rem - eo;
          BATCH4(zc, ec, eo, r4);
        }
      }
    }
    float outd = w / (s + 1e-16f) + zncur;  // empty segment -> zn
    aggh[((size_t)cur << 6) + d] = __float2half(outd);
    if (!more) break;
    cur = nxt; beg = begN; deg = degN; zncur = znN;
    nxt = nxt2; begN = beg2; degN = deg2; srcN = src2;
    b ^= 1;
  }
}

// MLP: grid-stride tiles of 32 nodes (8/wave); weights fp16 in LDS [red][out];
// fdot2 (fp32-accum) GEMMs; fp16 activations staged by one global_load_lds per wave.
template <int RESID, int LASTL>
__global__ void mlp_kernel(const __half* __restrict__ aggh, float* __restrict__ hbuf,
                           __half* __restrict__ zout, const __half2* __restrict__ w1p,
                           const __half2* __restrict__ w2p, const float* __restrict__ b1,
                           const float* __restrict__ g1, const float* __restrict__ bb1,
                           const float* __restrict__ b2, const float* __restrict__ nlg,
                           const float* __restrict__ nlb, int N, int ntiles) {
  __shared__ __align__(16) h2 w1s[32 * 128];  // 16 KB [g][j]
  __shared__ __align__(16) h2 w2s[64 * 64];   // 16 KB [g][j]
  __shared__ __align__(16) h2 zs[4][512];     // 2 KB/wave
  int wv = threadIdx.x >> 6, d = threadIdx.x & 63;
  {
    const char* gp1 = (const char*)w1p;
    const char* gp2 = (const char*)w2p;
    for (int i = wv; i < 16; i += 4) {
      gload_lds16(gp1 + (i << 10) + (d << 4), (char*)w1s + (i << 10));
      gload_lds16(gp2 + (i << 10) + (d << 4), (char*)w2s + (i << 10));
    }
  }
  asm volatile("s_waitcnt vmcnt(0)" ::: "memory");
  __syncthreads();
  float bb0 = b1[d], bb64 = b1[64 + d];
  float g1d = g1[d], g1d64 = g1[64 + d], bb1d = bb1[d], bb1d64 = bb1[64 + d];
  float b2d = b2[d];
  float g0 = nlg[d], bb = nlb[d];
  const float4* af4 = reinterpret_cast<const float4*>(&zs[wv][0]);
  __half* zhp = reinterpret_cast<__half*>(&zs[wv][0]);

  for (int tile = blockIdx.x; tile < ntiles; tile += gridDim.x) {
    int n0 = tile * 32 + wv * 8;
    if (n0 >= N) continue;
    asm volatile("s_waitcnt lgkmcnt(0)" ::: "memory");  // prior tile's z reads done
    gload_lds16((const char*)(aggh + ((size_t)n0 << 6)) + (d << 4), (char*)&zs[wv][0]);
    asm volatile("s_waitcnt vmcnt(0)" ::: "memory");
    float y0[MTILE], y1[MTILE];
#pragma unroll
    for (int j = 0; j < MTILE; ++j) { y0[j] = bb0; y1[j] = bb64; }
    // GEMM1: 8 iters x 8 dd (4 h2-pairs)
    for (int ii = 0; ii < 8; ++ii) {
      h2 wA0 = w1s[(4 * ii + 0) * 128 + d], wA1 = w1s[(4 * ii + 1) * 128 + d];
      h2 wA2 = w1s[(4 * ii + 2) * 128 + d], wA3 = w1s[(4 * ii + 3) * 128 + d];
      h2 wB0 = w1s[(4 * ii + 0) * 128 + 64 + d], wB1 = w1s[(4 * ii + 1) * 128 + 64 + d];
      h2 wB2 = w1s[(4 * ii + 2) * 128 + 64 + d], wB3 = w1s[(4 * ii + 3) * 128 + 64 + d];
#pragma unroll
      for (int j = 0; j < MTILE; ++j) {
        float4 av = af4[j * 8 + ii];  // broadcast 8 halves of a[j]
        h2 a0 = __builtin_bit_cast(h2, av.x), a1 = __builtin_bit_cast(h2, av.y);
        h2 a2 = __builtin_bit_cast(h2, av.z), a3 = __builtin_bit_cast(h2, av.w);
        y0[j] = fdot2f(a3, wA3, fdot2f(a2, wA2, fdot2f(a1, wA1, fdot2f(a0, wA0, y0[j]))));
        y1[j] = fdot2f(a3, wB3, fdot2f(a2, wB2, fdot2f(a1, wB1, fdot2f(a0, wB0, y1[j]))));
      }
    }
    // LN128 + relu -> z (fp16, overwrites a region; a is dead)
    for (int j = 0; j < MTILE; ++j) {
      float mu = wred(y0[j] + y1[j]) * (1.f / 128.f);
      float d0 = y0[j] - mu, d1 = y1[j] - mu;
      float var = wred(d0 * d0 + d1 * d1) * (1.f / 128.f);
      float r = rsqrtf(var + 1e-5f);
      float z0 = fmaxf(d0 * r * g1d + bb1d, 0.f);
      float z1 = fmaxf(d1 * r * g1d64 + bb1d64, 0.f);
      zhp[j * 128 + d] = __float2half(z0);
      zhp[j * 128 + 64 + d] = __float2half(z1);
    }
    // GEMM2: 16 iters x 8 k
    float o2[MTILE];
#pragma unroll
    for (int j = 0; j < MTILE; ++j) o2[j] = b2d;
    for (int ii = 0; ii < 16; ++ii) {
      h2 w0 = w2s[(4 * ii + 0) * 64 + d], w1v = w2s[(4 * ii + 1) * 64 + d];
      h2 w2v = w2s[(4 * ii + 2) * 64 + d], w3 = w2s[(4 * ii + 3) * 64 + d];
#pragma unroll
      for (int j = 0; j < MTILE; ++j) {
        float4 zv = af4[j * 16 + ii];
        h2 z0 = __builtin_bit_cast(h2, zv.x), z1 = __builtin_bit_cast(h2, zv.y);
        h2 z2 = __builtin_bit_cast(h2, zv.z), z3 = __builtin_bit_cast(h2, zv.w);
        o2[j] = fdot2f(z3, w3, fdot2f(z2, w2v, fdot2f(z1, w1v, fdot2f(z0, w0, o2[j]))));
      }
    }
    for (int j = 0; j < MTILE; ++j) {
      int n = n0 + j;
      if (n >= N) break;
      float hb = RESID ? hbuf[((size_t)n << 6) + d] : 0.f;
      float hnew = hb + o2[j];
      if (!LASTL) hbuf[((size_t)n << 6) + d] = hnew;
      float mu = wred(hnew) * (1.f / 64.f);
      float dd2 = hnew - mu;
      float var = wred(dd2 * dd2) * (1.f / 64.f);
      float r2 = rsqrtf(var + 1e-5f);
      zout[((size_t)n << 6) + d] = __float2half(fmaxf(dd2 * r2 * g0 + bb, 0.f));
    }
  }
}

// out = z @ lin_W + lin_b; MTILE nodes/wave, lin weights staged in LDS (fp16 packed).
__global__ void final_kernel(const __half* __restrict__ zh, const __half2* __restrict__ linp,
                             const float* __restrict__ linb, float* __restrict__ out, int N) {
  __shared__ __align__(16) __half2 lins[32 * 112 + 32];
  __shared__ __half zsh[4][MTILE * 64];
  int wv = threadIdx.x >> 6, d = threadIdx.x & 63;
  {
    const char* gp = (const char*)linp;
    for (int i = wv; i < 14; i += 4)
      gload_lds16(gp + (i << 10) + (d << 4), (char*)lins + (i << 10));
  }
  asm volatile("s_waitcnt vmcnt(0)" ::: "memory");
  __syncthreads();
  int n0 = (blockIdx.x * 4 + wv) * MTILE;
  if (n0 >= N) return;
  for (int j = 0; j < MTILE; ++j) {
    int n = min(n0 + j, N - 1);
    zsh[wv][j * 64 + d] = zh[((size_t)n << 6) + d];
  }
  float a0[MTILE], a1[MTILE];
  float lb0 = linb[d];
  float lb1 = (d < 48) ? linb[64 + d] : 0.f;
#pragma unroll
  for (int j = 0; j < MTILE; ++j) { a0[j] = lb0; a1[j] = lb1; }
  for (int g = 0; g < 32; ++g) {
    float2 w0 = __half22float2(lins[g * 112 + d]);
    float2 w1 = __half22float2(lins[g * 112 + 64 + d]);  // d>=48 reads pad, unused
#pragma unroll
    for (int j = 0; j < MTILE; ++j) {
      float2 zz = __half22float2(*reinterpret_cast<const __half2*>(&zsh[wv][j * 64 + 2 * g]));
      a0[j] = fmaf(zz.x, w0.x, a0[j]); a0[j] = fmaf(zz.y, w0.y, a0[j]);
      a1[j] = fmaf(zz.x, w1.x, a1[j]); a1[j] = fmaf(zz.y, w1.y, a1[j]);
    }
  }
  for (int j = 0; j < MTILE; ++j) {
    int n = n0 + j;
    if (n >= N) break;
    size_t b = (size_t)n * 112;
    out[b + d] = a0[j];
    if (d < 48) out[b + 64 + d] = a1[j];
  }
}

extern "C" void kernel_launch(void* const* d_in, const int* in_sizes, int n_in, void* d_out,
                              int out_size, void* d_ws, size_t ws_size, hipStream_t stream) {
  const float* x = (const float*)d_in[0];
  const float* eattr = (const float*)d_in[1];
  const int* ei = (const int*)d_in[2];
  const float* node_W = (const float*)d_in[3];
  const float* node_b = (const float*)d_in[4];
  const float* edge_W = (const float*)d_in[5];
  const float* edge_b = (const float*)d_in[6];
  const float* tptr = (const float*)d_in[7];
  const float* W1 = (const float*)d_in[8];
  const float* b1 = (const float*)d_in[9];
  const float* g1 = (const float*)d_in[10];
  const float* bb1 = (const float*)d_in[11];
  const float* W2 = (const float*)d_in[12];
  const float* b2 = (const float*)d_in[13];
  const float* lng = (const float*)d_in[14];
  const float* lnb = (const float*)d_in[15];
  const float* linW = (const float*)d_in[16];
  const float* linb = (const float*)d_in[17];
  const int N = in_sizes[0] / 8;
  const int E = in_sizes[1] / 8;
  const int* srcp = ei;
  const int* dstp = ei + E;

  char* ws = (char*)d_ws;
  size_t o = 0;
  auto alloc = [&](size_t bytes) {
    void* p = ws + o;
    o += (bytes + 255) & ~(size_t)255;
    return p;
  };
  const int nb = (N + 1023) / 1024;
  int* off = (int*)alloc((size_t)(N + 1) * 4);
  int* cnt = (int*)alloc((size_t)N * 4);
  int* bsum = (int*)alloc((size_t)nb * 4);
  int* boff = (int*)alloc((size_t)(nb + 1) * 4);
  int* csr_src = (int*)alloc((size_t)E * 4);
  __half* zh0 = (__half*)alloc((size_t)N * 64 * 2);
  __half* zh1 = (__half*)alloc((size_t)N * 64 * 2);
  __half* aggh = (__half*)alloc((size_t)N * 64 * 2 + 2048);  // slack for mlp stage over-read
  float* hbuf = (float*)alloc((size_t)N * 64 * 4);
  __half2* w1p = (__half2*)alloc((size_t)5 * 4096 * 4);
  __half2* w2p = (__half2*)alloc((size_t)5 * 4096 * 4);
  __half2* linp = (__half2*)alloc((size_t)32 * 112 * 4 + 256);
  __half* ecsr = (__half*)alloc((size_t)E * 16 + 2048);  // fp16 rows + staging slack

  int nbm = (N + 4 * MTILE - 1) / (4 * MTILE);
  int ntiles = (N + 31) / 32;
  int TW = AGG_BLOCKS * WPB;
  const int wprep_elems = 2 * 5 * 32 * 128 + 32 * 112;
  int nbe = (N * 64 + wprep_elems + 255) / 256;

  enc_prep_kernel<<<nbe, 256, 0, stream>>>(x, node_W, node_b, zh0, cnt, W1, W2, linW, w1p,
                                           w2p, linp, N);
  hist_kernel<<<(E + 255) / 256, 256, 0, stream>>>(dstp, cnt, E);
  scanA_kernel<<<nb, 1024, 0, stream>>>(cnt, off, bsum, N);
  scanB_kernel<<<1, 64, 0, stream>>>(bsum, boff, nb);
  scanC_kernel<<<(N + 1 + 255) / 256, 256, 0, stream>>>(off, boff, cnt, N, nb);
  scatter_kernel<<<(E + 255) / 256, 256, 0, stream>>>(srcp, dstp, off, cnt, csr_src, eattr,
                                                      ecsr, E);

  const __half* zi[5] = {zh0, zh1, zh0, zh1, zh0};
  __half* zo[5] = {zh1, zh0, zh1, zh0, zh1};
#define LAYER(RES, LAST, l, NL)                                                             \
  do {                                                                                      \
    agg_kernel<<<AGG_BLOCKS, 256, 0, stream>>>(zi[l], aggh, off, csr_src, ecsr, edge_W,     \
                                               edge_b, tptr, l, N, TW);                     \
    mlp_kernel<RES, LAST><<<MLP_BLOCKS, 256, 0, stream>>>(                                  \
        aggh, hbuf, zo[l], w1p + (l)*4096, w2p + (l)*4096, b1 + (l)*128, g1 + (l)*128,      \
        bb1 + (l)*128, b2 + (l)*64, lng + (NL)*64, lnb + (NL)*64, N, ntiles);               \
  } while (0)

  LAYER(0, 0, 0, 1);
  LAYER(1, 0, 1, 2);
  LAYER(1, 0, 2, 3);
  LAYER(1, 0, 3, 4);
  LAYER(1, 1, 4, 0);  // last layer applies layer-0 norm for the head
  final_kernel<<<nbm, 256, 0, stream>>>(zo[4], linp, linb, (float*)d_out, N);
}